// Round 7
// baseline (276.306 us; speedup 1.0000x reference)
//
#include <hip/hip_runtime.h>
#include <hip/hip_bf16.h>

#define B_SZ 8
#define T_SZ 1024
#define D_IN 512
#define D_H  64
#define N_H  8

typedef __hip_bfloat16 bf16;
using short8  = __attribute__((ext_vector_type(8))) short;
using short4v = __attribute__((ext_vector_type(4))) short;
using f32x4   = __attribute__((ext_vector_type(4))) float;

__device__ __forceinline__ unsigned short f2bf(float f) {
    union { __hip_bfloat16 b; unsigned short u; } c;
    c.b = __float2bfloat16(f);
    return c.u;
}

// ---------------------------------------------------------------------------
// prep: W[i][d][h] fp32 -> Wt[mat][n=h*64+d][k=i] bf16 (1.5 MB), plus
// padf[b][t] = -1000 if key_seq==-1 else 0.  grid (1024, 3) x 256.
// ---------------------------------------------------------------------------
__global__ __launch_bounds__(256) void prep_kernel(
    const float* __restrict__ Wk, const float* __restrict__ Wq,
    const float* __restrict__ Wv, const int* __restrict__ key_seq,
    unsigned short* __restrict__ Wt, float* __restrict__ padf)
{
    const int mat = blockIdx.y;
    const float* W = (mat == 0) ? Wk : (mat == 1) ? Wq : Wv;
    int idx = blockIdx.x * 256 + threadIdx.x;        // 0..262143
    float v = W[idx];
    int k = idx >> 9, c = idx & 511;                 // c = d*8 + h
    int h = c & 7, d = c >> 3;
    Wt[(((size_t)mat * 8 + h) * 64 + d) * 512 + k] = f2bf(v);
    if (mat == 2 && idx < B_SZ * T_SZ)
        padf[idx] = (key_seq[idx] == -1) ? -1000.f : 0.f;
}

// ---------------------------------------------------------------------------
// MFMA projection, 128x128 tiles. grid (8192/128, 3*4), block 256 (2x2 waves,
// wave tile 64x64). mat 0 -> Kb[bh][t][d]; mat 1 -> Qb[bh][t][d];
// mat 2 -> Vt[bh][d][t] (transposed in the epilogue; vt_kernel eliminated).
// ---------------------------------------------------------------------------
__global__ __launch_bounds__(256) void proj_kernel(
    const float* __restrict__ keys, const float* __restrict__ queries,
    const float* __restrict__ values,
    const unsigned short* __restrict__ Wt, unsigned short* __restrict__ KQVb)
{
    const int tid = threadIdx.x;
    const int m0  = blockIdx.x * 128;
    const int mat = blockIdx.y >> 2, ntile = blockIdx.y & 3;
    const int n0  = ntile * 128;

    const float* X = (mat == 0) ? keys : (mat == 1) ? queries : values;
    const unsigned short* WTm = Wt + (size_t)mat * 512 * 512;   // [n][k]
    const size_t per = (size_t)B_SZ * N_H * T_SZ * D_H;
    unsigned short* P = KQVb + (size_t)mat * per;

    __shared__ __align__(16) unsigned short Ast[128 * 72];
    __shared__ __align__(16) unsigned short Bst[128 * 72];

    const int wid = tid >> 6, lane = tid & 63;
    const int quad = lane >> 4, l15 = lane & 15;
    const int wm = wid >> 1, wn = wid & 1;

    f32x4 acc[4][4];
    #pragma unroll
    for (int i = 0; i < 4; ++i)
        #pragma unroll
        for (int j = 0; j < 4; ++j) acc[i][j] = (f32x4){0.f, 0.f, 0.f, 0.f};

    const float4* X4 = (const float4*)X;

    for (int kc = 0; kc < 8; ++kc) {
        const int k0 = kc * 64;
        __syncthreads();
        #pragma unroll
        for (int q = 0; q < 8; ++q) {                // A: 128 x 64, fp32->bf16
            int e = tid + q * 256;
            int r = e >> 4, c4 = e & 15;
            float4 v = X4[(size_t)(m0 + r) * (D_IN / 4) + (k0 >> 2) + c4];
            short4v s = {(short)f2bf(v.x), (short)f2bf(v.y),
                         (short)f2bf(v.z), (short)f2bf(v.w)};
            *(short4v*)&Ast[r * 72 + c4 * 4] = s;
        }
        #pragma unroll
        for (int q = 0; q < 4; ++q) {                // B: 128 x 64, b128 copies
            int e = tid + q * 256;
            int r = e >> 3, ch = e & 7;
            *(short8*)&Bst[r * 72 + ch * 8] =
                *(const short8*)&WTm[(size_t)(n0 + r) * 512 + k0 + ch * 8];
        }
        __syncthreads();
        #pragma unroll
        for (int kc2 = 0; kc2 < 2; ++kc2) {
            short8 af[4], bfr[4];
            #pragma unroll
            for (int mt = 0; mt < 4; ++mt)
                af[mt] = *(const short8*)&Ast[(wm*64 + mt*16 + l15) * 72 + kc2*32 + quad*8];
            #pragma unroll
            for (int nt = 0; nt < 4; ++nt)
                bfr[nt] = *(const short8*)&Bst[(wn*64 + nt*16 + l15) * 72 + kc2*32 + quad*8];
            #pragma unroll
            for (int mt = 0; mt < 4; ++mt)
                #pragma unroll
                for (int nt = 0; nt < 4; ++nt)
                    acc[mt][nt] = __builtin_amdgcn_mfma_f32_16x16x32_bf16(
                        af[mt], bfr[nt], acc[mt][nt], 0, 0, 0);
        }
    }

    if (mat != 2) {
        #pragma unroll
        for (int mt = 0; mt < 4; ++mt)
            #pragma unroll
            for (int r = 0; r < 4; ++r) {
                int m = m0 + wm * 64 + mt * 16 + quad * 4 + r;
                int bb = m >> 10, t = m & 1023;
                #pragma unroll
                for (int nt = 0; nt < 4; ++nt) {
                    int n = n0 + wn * 64 + nt * 16 + l15;
                    int h = n >> 6, d = n & 63;
                    P[(((size_t)(bb * 8 + h)) * 1024 + t) * 64 + d] =
                        f2bf(acc[mt][nt][r]);
                }
            }
    } else {
        // V: write transposed Vt[bh][d][t], 4 consecutive t per short4v store
        #pragma unroll
        for (int mt = 0; mt < 4; ++mt) {
            int m = m0 + wm * 64 + mt * 16 + quad * 4;   // r = 0 base
            int bb = m >> 10, t = m & 1023;
            #pragma unroll
            for (int nt = 0; nt < 4; ++nt) {
                int n = n0 + wn * 64 + nt * 16 + l15;
                int h = n >> 6, d = n & 63;
                short4v s = {(short)f2bf(acc[mt][nt][0]),
                             (short)f2bf(acc[mt][nt][1]),
                             (short)f2bf(acc[mt][nt][2]),
                             (short)f2bf(acc[mt][nt][3])};
                *(short4v*)&P[(((size_t)(bb * 8 + h)) * 64 + d) * 1024 + t] = s;
            }
        }
    }
}

// ---------------------------------------------------------------------------
// Split-K MFMA flash attention with in-LDS merge.
// grid (64 jt, 64 bh), block 256 = 4 waves. Wave w handles key-chunk
// [256w, 256w+256) of the (bh, 16-query strip jt) problem, barrier-free
// (round-6 per-tile pipeline). One __syncthreads, then a 256-thread exact
// log-sum-exp merge of <=4 partials -> coalesced float4 output.
// ---------------------------------------------------------------------------
__global__ __launch_bounds__(256, 8) void attn_kernel(
    const unsigned short* __restrict__ Qb, const unsigned short* __restrict__ Kb,
    const unsigned short* __restrict__ Vt, const float* __restrict__ padf,
    float* __restrict__ out)
{
    const int jt  = blockIdx.x;            // query strip of 16
    const int bh  = blockIdx.y;
    const int j0  = jt * 16;
    const int b   = bh >> 3, h = bh & 7;
    const int tid = threadIdx.x;
    const int w   = tid >> 6, lane = tid & 63;
    const int quad = lane >> 4, l15 = lane & 15;

    // per-wave region: Pst (16x72 shorts, 2304B) then reused as
    // Olds (16x68 floats, 4352B). Time-disjoint within a wave.
    __shared__ __align__(16) char sreg[4][4352];
    __shared__ float2 mls[4][16];

    const int nc = (jt >> 4) + 1;          // live chunks (1..4)

    if (w < nc) {
        unsigned short* Pst = (unsigned short*)&sreg[w][0];
        const size_t bhT = (size_t)bh * T_SZ;
        const short8 qf0 = *(const short8*)&Qb[(bhT + j0 + l15) * 64 + quad * 8];
        const short8 qf1 = *(const short8*)&Qb[(bhT + j0 + l15) * 64 + 32 + quad * 8];
        const int jg = j0 + l15;
        const float SCALE = 0.125f * 1.44269504088896341f;  // /sqrt(64)*log2(e)

        const int c0 = w * 256;
        const int n_it = min(4, (j0 + 16 - c0 + 63) >> 6);

        float m = -1e30f, l = 0.f;
        f32x4 o0 = {0.f,0.f,0.f,0.f}, o1 = o0, o2 = o0, o3 = o0;

        for (int it = 0; it < n_it; ++it) {
            const int i0 = c0 + it * 64;

            // ---- scores S[i][j] = K.Q^T, frags direct from global ----
            float sv[16];
            #pragma unroll
            for (int st = 0; st < 4; ++st) {
                f32x4 s = {0.f, 0.f, 0.f, 0.f};
                short8 a0 = *(const short8*)&Kb[(bhT + i0 + st*16 + l15) * 64 + quad * 8];
                s = __builtin_amdgcn_mfma_f32_16x16x32_bf16(a0, qf0, s, 0, 0, 0);
                short8 a1 = *(const short8*)&Kb[(bhT + i0 + st*16 + l15) * 64 + 32 + quad * 8];
                s = __builtin_amdgcn_mfma_f32_16x16x32_bf16(a1, qf1, s, 0, 0, 0);
                float4 pd4 = *(const float4*)&padf[b * T_SZ + i0 + st*16 + quad*4];
                float pdv[4] = {pd4.x, pd4.y, pd4.z, pd4.w};
                #pragma unroll
                for (int r = 0; r < 4; ++r) {
                    int iloc = st * 16 + quad * 4 + r;
                    float v = s[r] + pdv[r];
                    if (i0 + iloc > jg) v -= 1000.f;     // causal, pre-scale
                    sv[st * 4 + r] = v * SCALE;          // exp2 domain
                }
            }

            // ---- online softmax (per j = l15; combine quads via shfl) ----
            float mt = sv[0];
            #pragma unroll
            for (int k = 1; k < 16; ++k) mt = fmaxf(mt, sv[k]);
            mt = fmaxf(mt, __shfl_xor(mt, 16));
            mt = fmaxf(mt, __shfl_xor(mt, 32));
            const float mnew  = fmaxf(m, mt);
            const float alpha = exp2f(m - mnew);
            float p[16], ls = 0.f;
            #pragma unroll
            for (int k = 0; k < 16; ++k) { p[k] = exp2f(sv[k] - mnew); ls += p[k]; }
            ls += __shfl_xor(ls, 16);
            ls += __shfl_xor(ls, 32);
            l = l * alpha + ls;
            m = mnew;
            o0 *= alpha; o1 *= alpha; o2 *= alpha; o3 *= alpha;

            // ---- P^T into wave-private LDS (2-way banks = free) ----
            #pragma unroll
            for (int st = 0; st < 4; ++st) {
                short4v pk = {(short)f2bf(p[st*4+0]), (short)f2bf(p[st*4+1]),
                              (short)f2bf(p[st*4+2]), (short)f2bf(p[st*4+3])};
                *(short4v*)&Pst[l15 * 72 + st * 16 + quad * 4] = pk;
            }
            const short8 pf0 = *(const short8*)&Pst[l15 * 72 + quad * 8];
            const short8 pf1 = *(const short8*)&Pst[l15 * 72 + 32 + quad * 8];

            // ---- PV: O^T[d][j] += V^T x P, frags direct from global ----
            short8 a;
            a = *(const short8*)&Vt[((size_t)bh*64 +  0 + l15) * 1024 + i0 + quad*8];
            o0 = __builtin_amdgcn_mfma_f32_16x16x32_bf16(a, pf0, o0, 0, 0, 0);
            a = *(const short8*)&Vt[((size_t)bh*64 +  0 + l15) * 1024 + i0 + 32 + quad*8];
            o0 = __builtin_amdgcn_mfma_f32_16x16x32_bf16(a, pf1, o0, 0, 0, 0);
            a = *(const short8*)&Vt[((size_t)bh*64 + 16 + l15) * 1024 + i0 + quad*8];
            o1 = __builtin_amdgcn_mfma_f32_16x16x32_bf16(a, pf0, o1, 0, 0, 0);
            a = *(const short8*)&Vt[((size_t)bh*64 + 16 + l15) * 1024 + i0 + 32 + quad*8];
            o1 = __builtin_amdgcn_mfma_f32_16x16x32_bf16(a, pf1, o1, 0, 0, 0);
            a = *(const short8*)&Vt[((size_t)bh*64 + 32 + l15) * 1024 + i0 + quad*8];
            o2 = __builtin_amdgcn_mfma_f32_16x16x32_bf16(a, pf0, o2, 0, 0, 0);
            a = *(const short8*)&Vt[((size_t)bh*64 + 32 + l15) * 1024 + i0 + 32 + quad*8];
            o2 = __builtin_amdgcn_mfma_f32_16x16x32_bf16(a, pf1, o2, 0, 0, 0);
            a = *(const short8*)&Vt[((size_t)bh*64 + 48 + l15) * 1024 + i0 + quad*8];
            o3 = __builtin_amdgcn_mfma_f32_16x16x32_bf16(a, pf0, o3, 0, 0, 0);
            a = *(const short8*)&Vt[((size_t)bh*64 + 48 + l15) * 1024 + i0 + 32 + quad*8];
            o3 = __builtin_amdgcn_mfma_f32_16x16x32_bf16(a, pf1, o3, 0, 0, 0);
        }

        // ---- deposit partial: Olds[j][d] (stride 68, 2-way banks) ----
        float* Olds = (float*)&sreg[w][0];
        *(float4*)&Olds[l15 * 68 +  0 + quad * 4] = (float4){o0[0], o0[1], o0[2], o0[3]};
        *(float4*)&Olds[l15 * 68 + 16 + quad * 4] = (float4){o1[0], o1[1], o1[2], o1[3]};
        *(float4*)&Olds[l15 * 68 + 32 + quad * 4] = (float4){o2[0], o2[1], o2[2], o2[3]};
        *(float4*)&Olds[l15 * 68 + 48 + quad * 4] = (float4){o3[0], o3[1], o3[2], o3[3]};
        if (quad == 0) mls[w][l15] = make_float2(m, l);
    }
    __syncthreads();

    // ---- exact merge of <=4 partials; thread = (j = tid>>4, dg = tid&15) ----
    const int j  = tid >> 4;
    const int dg = tid & 15;
    float M = -1e30f;
    for (int c = 0; c < nc; ++c) M = fmaxf(M, mls[c][j].x);
    float L = 0.f;
    float4 acc = {0.f, 0.f, 0.f, 0.f};
    for (int c = 0; c < nc; ++c) {
        float2 ml = mls[c][j];
        float sc = exp2f(ml.x - M);
        L += sc * ml.y;
        const float* Ol = (const float*)&sreg[c][0];
        float4 oc = *(const float4*)&Ol[j * 68 + dg * 4];
        acc.x += sc * oc.x; acc.y += sc * oc.y;
        acc.z += sc * oc.z; acc.w += sc * oc.w;
    }
    const float inv = 1.f / L;
    *(float4*)&out[(((size_t)b * 1024 + j0 + j) * 512) + h * 64 + dg * 4] =
        (float4){acc.x * inv, acc.y * inv, acc.z * inv, acc.w * inv};
}

// ---------------------------------------------------------------------------
extern "C" void kernel_launch(void* const* d_in, const int* in_sizes, int n_in,
                              void* d_out, int out_size, void* d_ws, size_t ws_size,
                              hipStream_t stream) {
    const float* keys    = (const float*)d_in[0];
    const float* queries = (const float*)d_in[1];
    const float* values  = (const float*)d_in[2];
    const float* Wk      = (const float*)d_in[3];
    const float* Wq      = (const float*)d_in[4];
    const float* Wv      = (const float*)d_in[5];
    const int*   key_seq = (const int*)d_in[6];

    const size_t per = (size_t)B_SZ * N_H * T_SZ * D_H;   // 4,194,304 elems
    unsigned short* Kb = (unsigned short*)d_ws;
    unsigned short* Qb = Kb + per;
    unsigned short* Vt = Kb + 2 * per;                    // transposed V
    unsigned short* Wt = Kb + 3 * per;                    // 786432 elems
    float*          padf = (float*)(Wt + 3 * 512 * 512);  // 16B-aligned

    prep_kernel<<<dim3(1024, 3), 256, 0, stream>>>(Wk, Wq, Wv, key_seq, Wt, padf);
    proj_kernel<<<dim3((B_SZ * T_SZ) / 128, 12), 256, 0, stream>>>(
        keys, queries, values, Wt, Kb);
    attn_kernel<<<dim3(64, 64), 256, 0, stream>>>(Qb, Kb, Vt, padf, (float*)d_out);
}

// Round 8
// 202.661 us; speedup vs baseline: 1.3634x; 1.3634x over previous
//
#include <hip/hip_runtime.h>
#include <hip/hip_bf16.h>

#define B_SZ 8
#define T_SZ 1024
#define D_IN 512
#define D_H  64
#define N_H  8

typedef __hip_bfloat16 bf16;
using short8  = __attribute__((ext_vector_type(8))) short;
using short4v = __attribute__((ext_vector_type(4))) short;
using f32x4   = __attribute__((ext_vector_type(4))) float;

__device__ __forceinline__ unsigned short f2bf(float f) {
    union { __hip_bfloat16 b; unsigned short u; } c;
    c.b = __float2bfloat16(f);
    return c.u;
}

// ---------------------------------------------------------------------------
// prep: W[i][d][h] fp32 -> Wt[mat][n=h*64+d][k=i] bf16 (1.5 MB), plus
// padf[b][t] = -1000 if key_seq==-1 else 0.  grid (1024, 3) x 256.
// ---------------------------------------------------------------------------
__global__ __launch_bounds__(256) void prep_kernel(
    const float* __restrict__ Wk, const float* __restrict__ Wq,
    const float* __restrict__ Wv, const int* __restrict__ key_seq,
    unsigned short* __restrict__ Wt, float* __restrict__ padf)
{
    const int mat = blockIdx.y;
    const float* W = (mat == 0) ? Wk : (mat == 1) ? Wq : Wv;
    int idx = blockIdx.x * 256 + threadIdx.x;        // 0..262143
    float v = W[idx];
    int k = idx >> 9, c = idx & 511;                 // c = d*8 + h
    int h = c & 7, d = c >> 3;
    Wt[(((size_t)mat * 8 + h) * 64 + d) * 512 + k] = f2bf(v);
    if (mat == 2 && idx < B_SZ * T_SZ)
        padf[idx] = (key_seq[idx] == -1) ? -1000.f : 0.f;
}

// ---------------------------------------------------------------------------
// MFMA projection, 128x128 tiles. grid (8192/128, 3*4), block 256 (2x2 waves,
// wave tile 64x64). mat 0 -> Kb[bh][t][d]; mat 1 -> Qb[bh][t][d];
// mat 2 -> Vt[bh][d][t] (transposed in the epilogue).
// ---------------------------------------------------------------------------
__global__ __launch_bounds__(256) void proj_kernel(
    const float* __restrict__ keys, const float* __restrict__ queries,
    const float* __restrict__ values,
    const unsigned short* __restrict__ Wt, unsigned short* __restrict__ KQVb)
{
    const int tid = threadIdx.x;
    const int m0  = blockIdx.x * 128;
    const int mat = blockIdx.y >> 2, ntile = blockIdx.y & 3;
    const int n0  = ntile * 128;

    const float* X = (mat == 0) ? keys : (mat == 1) ? queries : values;
    const unsigned short* WTm = Wt + (size_t)mat * 512 * 512;   // [n][k]
    const size_t per = (size_t)B_SZ * N_H * T_SZ * D_H;
    unsigned short* P = KQVb + (size_t)mat * per;

    __shared__ __align__(16) unsigned short Ast[128 * 72];
    __shared__ __align__(16) unsigned short Bst[128 * 72];

    const int wid = tid >> 6, lane = tid & 63;
    const int quad = lane >> 4, l15 = lane & 15;
    const int wm = wid >> 1, wn = wid & 1;

    f32x4 acc[4][4];
    #pragma unroll
    for (int i = 0; i < 4; ++i)
        #pragma unroll
        for (int j = 0; j < 4; ++j) acc[i][j] = (f32x4){0.f, 0.f, 0.f, 0.f};

    const float4* X4 = (const float4*)X;

    for (int kc = 0; kc < 8; ++kc) {
        const int k0 = kc * 64;
        __syncthreads();
        #pragma unroll
        for (int q = 0; q < 8; ++q) {                // A: 128 x 64, fp32->bf16
            int e = tid + q * 256;
            int r = e >> 4, c4 = e & 15;
            float4 v = X4[(size_t)(m0 + r) * (D_IN / 4) + (k0 >> 2) + c4];
            short4v s = {(short)f2bf(v.x), (short)f2bf(v.y),
                         (short)f2bf(v.z), (short)f2bf(v.w)};
            *(short4v*)&Ast[r * 72 + c4 * 4] = s;
        }
        #pragma unroll
        for (int q = 0; q < 4; ++q) {                // B: 128 x 64, b128 copies
            int e = tid + q * 256;
            int r = e >> 3, ch = e & 7;
            *(short8*)&Bst[r * 72 + ch * 8] =
                *(const short8*)&WTm[(size_t)(n0 + r) * 512 + k0 + ch * 8];
        }
        __syncthreads();
        #pragma unroll
        for (int kc2 = 0; kc2 < 2; ++kc2) {
            short8 af[4], bfr[4];
            #pragma unroll
            for (int mt = 0; mt < 4; ++mt)
                af[mt] = *(const short8*)&Ast[(wm*64 + mt*16 + l15) * 72 + kc2*32 + quad*8];
            #pragma unroll
            for (int nt = 0; nt < 4; ++nt)
                bfr[nt] = *(const short8*)&Bst[(wn*64 + nt*16 + l15) * 72 + kc2*32 + quad*8];
            #pragma unroll
            for (int mt = 0; mt < 4; ++mt)
                #pragma unroll
                for (int nt = 0; nt < 4; ++nt)
                    acc[mt][nt] = __builtin_amdgcn_mfma_f32_16x16x32_bf16(
                        af[mt], bfr[nt], acc[mt][nt], 0, 0, 0);
        }
    }

    if (mat != 2) {
        #pragma unroll
        for (int mt = 0; mt < 4; ++mt)
            #pragma unroll
            for (int r = 0; r < 4; ++r) {
                int m = m0 + wm * 64 + mt * 16 + quad * 4 + r;
                int bb = m >> 10, t = m & 1023;
                #pragma unroll
                for (int nt = 0; nt < 4; ++nt) {
                    int n = n0 + wn * 64 + nt * 16 + l15;
                    int h = n >> 6, d = n & 63;
                    P[(((size_t)(bb * 8 + h)) * 1024 + t) * 64 + d] =
                        f2bf(acc[mt][nt][r]);
                }
            }
    } else {
        // V: write transposed Vt[bh][d][t], 4 consecutive t per short4v store
        #pragma unroll
        for (int mt = 0; mt < 4; ++mt) {
            int m = m0 + wm * 64 + mt * 16 + quad * 4;   // r = 0 base
            int bb = m >> 10, t = m & 1023;
            #pragma unroll
            for (int nt = 0; nt < 4; ++nt) {
                int n = n0 + wn * 64 + nt * 16 + l15;
                int h = n >> 6, d = n & 63;
                short4v s = {(short)f2bf(acc[mt][nt][0]),
                             (short)f2bf(acc[mt][nt][1]),
                             (short)f2bf(acc[mt][nt][2]),
                             (short)f2bf(acc[mt][nt][3])};
                *(short4v*)&P[(((size_t)(bb * 8 + h)) * 64 + d) * 1024 + t] = s;
            }
        }
    }
}

// ---------------------------------------------------------------------------
// Split-K MFMA flash attention, round-robin tile assignment, in-LDS merge.
// 1D grid 4096, block 256 = 4 waves. Mapping (XCD-local K/V + longest-first):
//   b = x&7, h = (x>>3)&7, jt = 63 - (x>>6).
// Wave w handles i-tiles {w, w+4, w+8, ...} of [0, j0+16) barrier-free, then
// one __syncthreads and an exact log-sum-exp merge of <=4 partials.
// ---------------------------------------------------------------------------
__global__ __launch_bounds__(256) void attn_kernel(
    const unsigned short* __restrict__ Qb, const unsigned short* __restrict__ Kb,
    const unsigned short* __restrict__ Vt, const float* __restrict__ padf,
    float* __restrict__ out)
{
    const int x   = blockIdx.x;
    const int jt  = 63 - (x >> 6);
    const int b   = x & 7;
    const int h   = (x >> 3) & 7;
    const int bh  = b * 8 + h;
    const int j0  = jt * 16;
    const int tid = threadIdx.x;
    const int w   = tid >> 6, lane = tid & 63;
    const int quad = lane >> 4, l15 = lane & 15;

    // per-wave region: Pst (16x72 shorts) then reused as Olds (16x68 floats)
    __shared__ __align__(16) char sreg[4][4352];
    __shared__ float2 mls[4][16];

    const int ntiles = (j0 + 16 + 63) >> 6;        // 1..16
    {
        unsigned short* Pst = (unsigned short*)&sreg[w][0];
        const size_t bhT = (size_t)bh * T_SZ;
        const short8 qf0 = *(const short8*)&Qb[(bhT + j0 + l15) * 64 + quad * 8];
        const short8 qf1 = *(const short8*)&Qb[(bhT + j0 + l15) * 64 + 32 + quad * 8];
        const int jg = j0 + l15;
        const float SCALE = 0.125f * 1.44269504088896341f;  // /sqrt(64)*log2(e)

        float m = -1e30f, l = 0.f;
        f32x4 o0 = {0.f,0.f,0.f,0.f}, o1 = o0, o2 = o0, o3 = o0;

        for (int it = w; it < ntiles; it += 4) {
            const int i0 = it * 64;

            // ---- scores S[i][j] = K.Q^T, frags direct from global ----
            float sv[16];
            #pragma unroll
            for (int st = 0; st < 4; ++st) {
                f32x4 s = {0.f, 0.f, 0.f, 0.f};
                short8 a0 = *(const short8*)&Kb[(bhT + i0 + st*16 + l15) * 64 + quad * 8];
                s = __builtin_amdgcn_mfma_f32_16x16x32_bf16(a0, qf0, s, 0, 0, 0);
                short8 a1 = *(const short8*)&Kb[(bhT + i0 + st*16 + l15) * 64 + 32 + quad * 8];
                s = __builtin_amdgcn_mfma_f32_16x16x32_bf16(a1, qf1, s, 0, 0, 0);
                float4 pd4 = *(const float4*)&padf[b * T_SZ + i0 + st*16 + quad*4];
                float pdv[4] = {pd4.x, pd4.y, pd4.z, pd4.w};
                #pragma unroll
                for (int r = 0; r < 4; ++r) {
                    int iloc = st * 16 + quad * 4 + r;
                    float v = s[r] + pdv[r];
                    if (i0 + iloc > jg) v -= 1000.f;     // causal, pre-scale
                    sv[st * 4 + r] = v * SCALE;          // exp2 domain
                }
            }

            // ---- online softmax (per j = l15; combine quads via shfl) ----
            float mt = sv[0];
            #pragma unroll
            for (int k = 1; k < 16; ++k) mt = fmaxf(mt, sv[k]);
            mt = fmaxf(mt, __shfl_xor(mt, 16));
            mt = fmaxf(mt, __shfl_xor(mt, 32));
            const float mnew  = fmaxf(m, mt);
            const float alpha = exp2f(m - mnew);
            float p[16], ls = 0.f;
            #pragma unroll
            for (int k = 0; k < 16; ++k) { p[k] = exp2f(sv[k] - mnew); ls += p[k]; }
            ls += __shfl_xor(ls, 16);
            ls += __shfl_xor(ls, 32);
            l = l * alpha + ls;
            m = mnew;
            o0 *= alpha; o1 *= alpha; o2 *= alpha; o3 *= alpha;

            // ---- P^T into wave-private LDS (2-way banks = free) ----
            #pragma unroll
            for (int st = 0; st < 4; ++st) {
                short4v pk = {(short)f2bf(p[st*4+0]), (short)f2bf(p[st*4+1]),
                              (short)f2bf(p[st*4+2]), (short)f2bf(p[st*4+3])};
                *(short4v*)&Pst[l15 * 72 + st * 16 + quad * 4] = pk;
            }
            const short8 pf0 = *(const short8*)&Pst[l15 * 72 + quad * 8];
            const short8 pf1 = *(const short8*)&Pst[l15 * 72 + 32 + quad * 8];

            // ---- PV: O^T[d][j] += V^T x P, frags direct from global ----
            short8 a;
            a = *(const short8*)&Vt[((size_t)bh*64 +  0 + l15) * 1024 + i0 + quad*8];
            o0 = __builtin_amdgcn_mfma_f32_16x16x32_bf16(a, pf0, o0, 0, 0, 0);
            a = *(const short8*)&Vt[((size_t)bh*64 +  0 + l15) * 1024 + i0 + 32 + quad*8];
            o0 = __builtin_amdgcn_mfma_f32_16x16x32_bf16(a, pf1, o0, 0, 0, 0);
            a = *(const short8*)&Vt[((size_t)bh*64 + 16 + l15) * 1024 + i0 + quad*8];
            o1 = __builtin_amdgcn_mfma_f32_16x16x32_bf16(a, pf0, o1, 0, 0, 0);
            a = *(const short8*)&Vt[((size_t)bh*64 + 16 + l15) * 1024 + i0 + 32 + quad*8];
            o1 = __builtin_amdgcn_mfma_f32_16x16x32_bf16(a, pf1, o1, 0, 0, 0);
            a = *(const short8*)&Vt[((size_t)bh*64 + 32 + l15) * 1024 + i0 + quad*8];
            o2 = __builtin_amdgcn_mfma_f32_16x16x32_bf16(a, pf0, o2, 0, 0, 0);
            a = *(const short8*)&Vt[((size_t)bh*64 + 32 + l15) * 1024 + i0 + 32 + quad*8];
            o2 = __builtin_amdgcn_mfma_f32_16x16x32_bf16(a, pf1, o2, 0, 0, 0);
            a = *(const short8*)&Vt[((size_t)bh*64 + 48 + l15) * 1024 + i0 + quad*8];
            o3 = __builtin_amdgcn_mfma_f32_16x16x32_bf16(a, pf0, o3, 0, 0, 0);
            a = *(const short8*)&Vt[((size_t)bh*64 + 48 + l15) * 1024 + i0 + 32 + quad*8];
            o3 = __builtin_amdgcn_mfma_f32_16x16x32_bf16(a, pf1, o3, 0, 0, 0);
        }

        // ---- deposit partial: Olds[j][d] (stride 68, 2-way banks) ----
        float* Olds = (float*)&sreg[w][0];
        *(float4*)&Olds[l15 * 68 +  0 + quad * 4] = (float4){o0[0], o0[1], o0[2], o0[3]};
        *(float4*)&Olds[l15 * 68 + 16 + quad * 4] = (float4){o1[0], o1[1], o1[2], o1[3]};
        *(float4*)&Olds[l15 * 68 + 32 + quad * 4] = (float4){o2[0], o2[1], o2[2], o2[3]};
        *(float4*)&Olds[l15 * 68 + 48 + quad * 4] = (float4){o3[0], o3[1], o3[2], o3[3]};
        if (quad == 0) mls[w][l15] = make_float2(m, l);
    }
    __syncthreads();

    // ---- exact merge of <=4 partials; thread = (j = tid>>4, dg = tid&15) ----
    const int nc = (ntiles < 4) ? ntiles : 4;
    const int j  = tid >> 4;
    const int dg = tid & 15;
    float M = -1e30f;
    for (int c = 0; c < nc; ++c) M = fmaxf(M, mls[c][j].x);
    float L = 0.f;
    float4 acc = {0.f, 0.f, 0.f, 0.f};
    for (int c = 0; c < nc; ++c) {
        float2 ml = mls[c][j];
        float sc = exp2f(ml.x - M);
        L += sc * ml.y;
        const float* Ol = (const float*)&sreg[c][0];
        float4 oc = *(const float4*)&Ol[j * 68 + dg * 4];
        acc.x += sc * oc.x; acc.y += sc * oc.y;
        acc.z += sc * oc.z; acc.w += sc * oc.w;
    }
    const float inv = 1.f / L;
    *(float4*)&out[(((size_t)b * 1024 + j0 + j) * 512) + h * 64 + dg * 4] =
        (float4){acc.x * inv, acc.y * inv, acc.z * inv, acc.w * inv};
}

// ---------------------------------------------------------------------------
extern "C" void kernel_launch(void* const* d_in, const int* in_sizes, int n_in,
                              void* d_out, int out_size, void* d_ws, size_t ws_size,
                              hipStream_t stream) {
    const float* keys    = (const float*)d_in[0];
    const float* queries = (const float*)d_in[1];
    const float* values  = (const float*)d_in[2];
    const float* Wk      = (const float*)d_in[3];
    const float* Wq      = (const float*)d_in[4];
    const float* Wv      = (const float*)d_in[5];
    const int*   key_seq = (const int*)d_in[6];

    const size_t per = (size_t)B_SZ * N_H * T_SZ * D_H;   // 4,194,304 elems
    unsigned short* Kb = (unsigned short*)d_ws;
    unsigned short* Qb = Kb + per;
    unsigned short* Vt = Kb + 2 * per;                    // transposed V
    unsigned short* Wt = Kb + 3 * per;                    // 786432 elems
    float*          padf = (float*)(Wt + 3 * 512 * 512);  // 16B-aligned

    prep_kernel<<<dim3(1024, 3), 256, 0, stream>>>(Wk, Wq, Wv, key_seq, Wt, padf);
    proj_kernel<<<dim3((B_SZ * T_SZ) / 128, 12), 256, 0, stream>>>(
        keys, queries, values, Wt, Kb);
    attn_kernel<<<dim3(64 * 64), 256, 0, stream>>>(Qb, Kb, Vt, padf, (float*)d_out);
}

// Round 9
// 198.703 us; speedup vs baseline: 1.3905x; 1.0199x over previous
//
#include <hip/hip_runtime.h>
#include <hip/hip_bf16.h>

#define B_SZ 8
#define T_SZ 1024
#define D_IN 512
#define D_H  64
#define N_H  8

typedef __hip_bfloat16 bf16;
using short8  = __attribute__((ext_vector_type(8))) short;
using short4v = __attribute__((ext_vector_type(4))) short;
using f32x4   = __attribute__((ext_vector_type(4))) float;

__device__ __forceinline__ unsigned short f2bf(float f) {
    union { __hip_bfloat16 b; unsigned short u; } c;
    c.b = __float2bfloat16(f);
    return c.u;
}
// cheap RNE bf16 (valid for finite non-NaN inputs — p in [0, ~1.5])
__device__ __forceinline__ unsigned short f2bf_rne(float f) {
    unsigned u = __builtin_bit_cast(unsigned, f);
    u += 0x7fff + ((u >> 16) & 1);
    return (unsigned short)(u >> 16);
}

#define EXP2_SCALE (0.125f * 1.44269504088896341f)       /* /sqrt(64)*log2e */
#define CAUSAL_C   (1000.0f * 0.125f * 1.44269504088896341f)

// ---------------------------------------------------------------------------
// prep: W[i][d][h] fp32 -> Wt[mat][n=h*64+d][k=i] bf16 (1.5 MB), plus
// padf[b][t] = -1000*SCALE (pre-scaled, exp2 domain) if key_seq==-1 else 0.
// ---------------------------------------------------------------------------
__global__ __launch_bounds__(256) void prep_kernel(
    const float* __restrict__ Wk, const float* __restrict__ Wq,
    const float* __restrict__ Wv, const int* __restrict__ key_seq,
    unsigned short* __restrict__ Wt, float* __restrict__ padf)
{
    const int mat = blockIdx.y;
    const float* W = (mat == 0) ? Wk : (mat == 1) ? Wq : Wv;
    int idx = blockIdx.x * 256 + threadIdx.x;        // 0..262143
    float v = W[idx];
    int k = idx >> 9, c = idx & 511;                 // c = d*8 + h
    int h = c & 7, d = c >> 3;
    Wt[(((size_t)mat * 8 + h) * 64 + d) * 512 + k] = f2bf(v);
    if (mat == 2 && idx < B_SZ * T_SZ)
        padf[idx] = (key_seq[idx] == -1) ? -CAUSAL_C : 0.f;
}

// ---------------------------------------------------------------------------
// MFMA projection, 128x128 tiles. grid (8192/128, 3*4), block 256 (2x2 waves,
// wave tile 64x64). mat 0 -> Kb[bh][t][d]; mat 1 -> Qb[bh][t][d];
// mat 2 -> Vt[bh][d][t] (transposed in the epilogue).
// ---------------------------------------------------------------------------
__global__ __launch_bounds__(256) void proj_kernel(
    const float* __restrict__ keys, const float* __restrict__ queries,
    const float* __restrict__ values,
    const unsigned short* __restrict__ Wt, unsigned short* __restrict__ KQVb)
{
    const int tid = threadIdx.x;
    const int m0  = blockIdx.x * 128;
    const int mat = blockIdx.y >> 2, ntile = blockIdx.y & 3;
    const int n0  = ntile * 128;

    const float* X = (mat == 0) ? keys : (mat == 1) ? queries : values;
    const unsigned short* WTm = Wt + (size_t)mat * 512 * 512;   // [n][k]
    const size_t per = (size_t)B_SZ * N_H * T_SZ * D_H;
    unsigned short* P = KQVb + (size_t)mat * per;

    __shared__ __align__(16) unsigned short Ast[128 * 72];
    __shared__ __align__(16) unsigned short Bst[128 * 72];

    const int wid = tid >> 6, lane = tid & 63;
    const int quad = lane >> 4, l15 = lane & 15;
    const int wm = wid >> 1, wn = wid & 1;

    f32x4 acc[4][4];
    #pragma unroll
    for (int i = 0; i < 4; ++i)
        #pragma unroll
        for (int j = 0; j < 4; ++j) acc[i][j] = (f32x4){0.f, 0.f, 0.f, 0.f};

    const float4* X4 = (const float4*)X;

    for (int kc = 0; kc < 8; ++kc) {
        const int k0 = kc * 64;
        __syncthreads();
        #pragma unroll
        for (int q = 0; q < 8; ++q) {                // A: 128 x 64, fp32->bf16
            int e = tid + q * 256;
            int r = e >> 4, c4 = e & 15;
            float4 v = X4[(size_t)(m0 + r) * (D_IN / 4) + (k0 >> 2) + c4];
            short4v s = {(short)f2bf(v.x), (short)f2bf(v.y),
                         (short)f2bf(v.z), (short)f2bf(v.w)};
            *(short4v*)&Ast[r * 72 + c4 * 4] = s;
        }
        #pragma unroll
        for (int q = 0; q < 4; ++q) {                // B: 128 x 64, b128 copies
            int e = tid + q * 256;
            int r = e >> 3, ch = e & 7;
            *(short8*)&Bst[r * 72 + ch * 8] =
                *(const short8*)&WTm[(size_t)(n0 + r) * 512 + k0 + ch * 8];
        }
        __syncthreads();
        #pragma unroll
        for (int kc2 = 0; kc2 < 2; ++kc2) {
            short8 af[4], bfr[4];
            #pragma unroll
            for (int mt = 0; mt < 4; ++mt)
                af[mt] = *(const short8*)&Ast[(wm*64 + mt*16 + l15) * 72 + kc2*32 + quad*8];
            #pragma unroll
            for (int nt = 0; nt < 4; ++nt)
                bfr[nt] = *(const short8*)&Bst[(wn*64 + nt*16 + l15) * 72 + kc2*32 + quad*8];
            #pragma unroll
            for (int mt = 0; mt < 4; ++mt)
                #pragma unroll
                for (int nt = 0; nt < 4; ++nt)
                    acc[mt][nt] = __builtin_amdgcn_mfma_f32_16x16x32_bf16(
                        af[mt], bfr[nt], acc[mt][nt], 0, 0, 0);
        }
    }

    if (mat != 2) {
        #pragma unroll
        for (int mt = 0; mt < 4; ++mt)
            #pragma unroll
            for (int r = 0; r < 4; ++r) {
                int m = m0 + wm * 64 + mt * 16 + quad * 4 + r;
                int bb = m >> 10, t = m & 1023;
                #pragma unroll
                for (int nt = 0; nt < 4; ++nt) {
                    int n = n0 + wn * 64 + nt * 16 + l15;
                    int h = n >> 6, d = n & 63;
                    P[(((size_t)(bb * 8 + h)) * 1024 + t) * 64 + d] =
                        f2bf(acc[mt][nt][r]);
                }
            }
    } else {
        // V: write transposed Vt[bh][d][t], 4 consecutive t per short4v store
        #pragma unroll
        for (int mt = 0; mt < 4; ++mt) {
            int m = m0 + wm * 64 + mt * 16 + quad * 4;   // r = 0 base
            int bb = m >> 10, t = m & 1023;
            #pragma unroll
            for (int nt = 0; nt < 4; ++nt) {
                int n = n0 + wn * 64 + nt * 16 + l15;
                int h = n >> 6, d = n & 63;
                short4v s = {(short)f2bf(acc[mt][nt][0]),
                             (short)f2bf(acc[mt][nt][1]),
                             (short)f2bf(acc[mt][nt][2]),
                             (short)f2bf(acc[mt][nt][3])};
                *(short4v*)&P[(((size_t)(bb * 8 + h)) * 64 + d) * 1024 + t] = s;
            }
        }
    }
}

// ---------------------------------------------------------------------------
// Split-K MFMA flash attention, NO-MAX softmax (scores statically bounded;
// masked scores pre-scaled to -180 in exp2 domain -> exp2 underflows to 0).
// 1D grid 4096, block 256 = 4 waves; b = x&7 (XCD-local), longest-first jt.
// Wave w: i-tiles {w, w+4, ...}; causal cmp only on the diagonal tile.
// Merge = plain sum of <=4 partials (no rescale needed).
// ---------------------------------------------------------------------------
__global__ __launch_bounds__(256) void attn_kernel(
    const unsigned short* __restrict__ Qb, const unsigned short* __restrict__ Kb,
    const unsigned short* __restrict__ Vt, const float* __restrict__ padf,
    float* __restrict__ out)
{
    const int x   = blockIdx.x;
    const int jt  = 63 - (x >> 6);
    const int b   = x & 7;
    const int h   = (x >> 3) & 7;
    const int bh  = b * 8 + h;
    const int j0  = jt * 16;
    const int tid = threadIdx.x;
    const int w   = tid >> 6, lane = tid & 63;
    const int quad = lane >> 4, l15 = lane & 15;

    // per-wave region: Pst (16x72 shorts) then reused as Olds (16x68 floats)
    __shared__ __align__(16) char sreg[4][4352];
    __shared__ float lsh[4][16];

    const int ntiles = (jt >> 2) + 1;              // 1..16

    unsigned short* Pst = (unsigned short*)&sreg[w][0];
    const unsigned short* Kbh = Kb + (size_t)bh * (T_SZ * 64);
    const unsigned short* Vbh = Vt + (size_t)bh * (64 * T_SZ);
    const float* padp = padf + b * T_SZ;

    const short8 qf0 = *(const short8*)&Qb[((size_t)bh * T_SZ + j0 + l15) * 64 + quad * 8];
    const short8 qf1 = *(const short8*)&Qb[((size_t)bh * T_SZ + j0 + l15) * 64 + 32 + quad * 8];
    const int jg = j0 + l15;

    // loop-invariant lane offsets (saddr+voffset addressing in the loop)
    int koff[4], voff[4];
    #pragma unroll
    for (int st = 0; st < 4; ++st) koff[st] = (st * 16 + l15) * 64 + quad * 8;
    #pragma unroll
    for (int dt = 0; dt < 4; ++dt) voff[dt] = (dt * 16 + l15) * 1024 + quad * 8;

    float l = 0.f;
    f32x4 o0 = {0.f,0.f,0.f,0.f}, o1 = o0, o2 = o0, o3 = o0;

    for (int it = w; it < ntiles; it += 4) {
        const int i0 = it * 64;
        const unsigned short* kb = Kbh + i0 * 64;
        const unsigned short* vb = Vbh + i0;

        // ---- scores: sv = fma(KQ^T, SCALE, pad)  (pad pre-scaled) ----
        float sv[16];
        #pragma unroll
        for (int st = 0; st < 4; ++st) {
            f32x4 s = {0.f, 0.f, 0.f, 0.f};
            short8 a0 = *(const short8*)(kb + koff[st]);
            s = __builtin_amdgcn_mfma_f32_16x16x32_bf16(a0, qf0, s, 0, 0, 0);
            short8 a1 = *(const short8*)(kb + koff[st] + 32);
            s = __builtin_amdgcn_mfma_f32_16x16x32_bf16(a1, qf1, s, 0, 0, 0);
            float4 pd = *(const float4*)&padp[i0 + st * 16 + quad * 4];
            sv[st*4+0] = fmaf(s[0], EXP2_SCALE, pd.x);
            sv[st*4+1] = fmaf(s[1], EXP2_SCALE, pd.y);
            sv[st*4+2] = fmaf(s[2], EXP2_SCALE, pd.z);
            sv[st*4+3] = fmaf(s[3], EXP2_SCALE, pd.w);
        }
        if (it == ntiles - 1) {                    // diagonal tile only
            #pragma unroll
            for (int st = 0; st < 4; ++st)
                #pragma unroll
                for (int r = 0; r < 4; ++r)
                    if (i0 + st * 16 + quad * 4 + r > jg)
                        sv[st*4+r] -= CAUSAL_C;
        }

        // ---- p = exp2(sv); accumulate l per-lane (reduce once at end) ----
        #pragma unroll
        for (int k = 0; k < 16; ++k) { sv[k] = exp2f(sv[k]); l += sv[k]; }

        // ---- P^T -> wave-private LDS -> B-frags ----
        #pragma unroll
        for (int st = 0; st < 4; ++st) {
            short4v pk = {(short)f2bf_rne(sv[st*4+0]), (short)f2bf_rne(sv[st*4+1]),
                          (short)f2bf_rne(sv[st*4+2]), (short)f2bf_rne(sv[st*4+3])};
            *(short4v*)&Pst[l15 * 72 + st * 16 + quad * 4] = pk;
        }
        const short8 pf0 = *(const short8*)&Pst[l15 * 72 + quad * 8];
        const short8 pf1 = *(const short8*)&Pst[l15 * 72 + 32 + quad * 8];

        // ---- PV: O^T[d][j] += V^T x P ----
        short8 a;
        a = *(const short8*)(vb + voff[0]);      o0 = __builtin_amdgcn_mfma_f32_16x16x32_bf16(a, pf0, o0, 0, 0, 0);
        a = *(const short8*)(vb + voff[0] + 32); o0 = __builtin_amdgcn_mfma_f32_16x16x32_bf16(a, pf1, o0, 0, 0, 0);
        a = *(const short8*)(vb + voff[1]);      o1 = __builtin_amdgcn_mfma_f32_16x16x32_bf16(a, pf0, o1, 0, 0, 0);
        a = *(const short8*)(vb + voff[1] + 32); o1 = __builtin_amdgcn_mfma_f32_16x16x32_bf16(a, pf1, o1, 0, 0, 0);
        a = *(const short8*)(vb + voff[2]);      o2 = __builtin_amdgcn_mfma_f32_16x16x32_bf16(a, pf0, o2, 0, 0, 0);
        a = *(const short8*)(vb + voff[2] + 32); o2 = __builtin_amdgcn_mfma_f32_16x16x32_bf16(a, pf1, o2, 0, 0, 0);
        a = *(const short8*)(vb + voff[3]);      o3 = __builtin_amdgcn_mfma_f32_16x16x32_bf16(a, pf0, o3, 0, 0, 0);
        a = *(const short8*)(vb + voff[3] + 32); o3 = __builtin_amdgcn_mfma_f32_16x16x32_bf16(a, pf1, o3, 0, 0, 0);
    }

    // single cross-quad l reduction (valid: quads partition i)
    l += __shfl_xor(l, 16);
    l += __shfl_xor(l, 32);

    // ---- deposit partial (unnormalized; merge is a plain sum) ----
    float* Olds = (float*)&sreg[w][0];
    *(float4*)&Olds[l15 * 68 +  0 + quad * 4] = (float4){o0[0], o0[1], o0[2], o0[3]};
    *(float4*)&Olds[l15 * 68 + 16 + quad * 4] = (float4){o1[0], o1[1], o1[2], o1[3]};
    *(float4*)&Olds[l15 * 68 + 32 + quad * 4] = (float4){o2[0], o2[1], o2[2], o2[3]};
    *(float4*)&Olds[l15 * 68 + 48 + quad * 4] = (float4){o3[0], o3[1], o3[2], o3[3]};
    if (quad == 0) lsh[w][l15] = l;
    __syncthreads();

    // ---- merge <=4 partials; thread = (j = tid>>4, dg = tid&15) ----
    const int nc = (ntiles < 4) ? ntiles : 4;
    const int j  = tid >> 4;
    const int dg = tid & 15;
    float L = 0.f;
    float4 acc = {0.f, 0.f, 0.f, 0.f};
    for (int c = 0; c < nc; ++c) {
        L += lsh[c][j];
        const float* Ol = (const float*)&sreg[c][0];
        float4 oc = *(const float4*)&Ol[j * 68 + dg * 4];
        acc.x += oc.x; acc.y += oc.y; acc.z += oc.z; acc.w += oc.w;
    }
    const float inv = 1.f / L;
    *(float4*)&out[(((size_t)b * 1024 + j0 + j) * 512) + h * 64 + dg * 4] =
        (float4){acc.x * inv, acc.y * inv, acc.z * inv, acc.w * inv};
}

// ---------------------------------------------------------------------------
extern "C" void kernel_launch(void* const* d_in, const int* in_sizes, int n_in,
                              void* d_out, int out_size, void* d_ws, size_t ws_size,
                              hipStream_t stream) {
    const float* keys    = (const float*)d_in[0];
    const float* queries = (const float*)d_in[1];
    const float* values  = (const float*)d_in[2];
    const float* Wk      = (const float*)d_in[3];
    const float* Wq      = (const float*)d_in[4];
    const float* Wv      = (const float*)d_in[5];
    const int*   key_seq = (const int*)d_in[6];

    const size_t per = (size_t)B_SZ * N_H * T_SZ * D_H;   // 4,194,304 elems
    unsigned short* Kb = (unsigned short*)d_ws;
    unsigned short* Qb = Kb + per;
    unsigned short* Vt = Kb + 2 * per;                    // transposed V
    unsigned short* Wt = Kb + 3 * per;                    // 786432 elems
    float*          padf = (float*)(Wt + 3 * 512 * 512);  // 16B-aligned

    prep_kernel<<<dim3(1024, 3), 256, 0, stream>>>(Wk, Wq, Wv, key_seq, Wt, padf);
    proj_kernel<<<dim3((B_SZ * T_SZ) / 128, 12), 256, 0, stream>>>(
        keys, queries, values, Wt, Kb);
    attn_kernel<<<dim3(64 * 64), 256, 0, stream>>>(Qb, Kb, Vt, padf, (float*)d_out);
}